// Round 10
// baseline (270.050 us; speedup 1.0000x reference)
//
#include <hip/hip_runtime.h>
#include <hip/hip_cooperative_groups.h>
#include <stdint.h>

#define ROUNDS 64
#define HIDDEN 256
#define BATCH  65536

typedef int   v4i  __attribute__((ext_vector_type(4)));
typedef int   v8i  __attribute__((ext_vector_type(8)));
typedef float v16f __attribute__((ext_vector_type(16)));
typedef unsigned long long u64;

namespace cg = cooperative_groups;

// ============================================================================
// ALGEBRAIC COLLAPSE (R8, verified exact): each round is an affine map over
// GF(2): s' = Whar s XOR n (Whar = (W!=0), -1 === 1 mod 2). Compose all 64:
// s_f = M s0 XOR c; apply (M,c) to the batch with the proven fp4-MFMA kernel.
// R9 lesson: the 6-launch serial chain cost ~100us of boundaries and each
// compose paid exposed global latency. R10: ONE cooperative dispatch runs the
// whole tree (16x4 -> 4x4 -> 1x4) with grid.sync() between levels, B-rows
// preloaded to registers, and packm inlined into block 0's tail.
// ============================================================================

// ws layout (bytes)
#define WB_OFF   0u        // W bits  [64][256][4] u64 = 512 KB
#define NB_OFF   524288u   // n bits  [64][4] u64      = 2 KB
#define G1M_OFF  526336u   // level-1 matrices [16][256][4] u64 = 128 KB
#define G1V_OFF  657408u   // level-1 vectors  [16][4] u64      = 512 B
#define G2M_OFF  657920u   // level-2 matrices [4][256][4] u64  = 32 KB
#define G2V_OFF  690688u   // level-2 vectors  [4][4] u64       = 128 B
#define WPK_OFF  690816u   // fp4 A-fragments [mt=8][ks=4][lane=64][16B] = 32 KB
#define NF_OFF   723584u   // noise floats [mt=8][lh=2][j=16] f32 = 1 KB

// sigma: nibble slot n (0..31) within a 32-k chunk holds logical k-offset
// rho(n). Applied identically to M-pack and state-pack so it cancels.
__host__ __device__ constexpr int rho(int n) {
  return 4 * (n >> 4) + (n & 3) + 8 * ((n >> 2) & 3);
}

// Per-C-slot bias (epilogue v_add_f32, IEEE-exact; round-1 FAILED note: bias
// must stay OUTSIDE the MFMA C-init). dot in [0,256] + c in {0,1}: exact.
__host__ __device__ constexpr float bias_q(int q) {
  return (q == 0) ? 6291456.0f   // 1.5*2^22 -> parity at bit 1
       : (q == 1) ? 393216.0f    // 1.5*2^18 -> bit 5
       : (q == 2) ? 24576.0f     // 1.5*2^14 -> bit 9
                  : 1536.0f;     // 1.5*2^10 -> bit 13
}

// ---- 1) bitpack: W floats -> row-major bit matrix; noise -> bit vectors ----
__global__ __launch_bounds__(256) void bitpack(const float* __restrict__ mat,
                                               const float* __restrict__ noi,
                                               u64* __restrict__ wb,
                                               u64* __restrict__ nb) {
  unsigned blk = blockIdx.x;
  if (blk >= 16384u) {  // noise: 64*256 bits
    unsigned tg = (blk - 16384u) * 256u + threadIdx.x;  // < 16384
    u64 m = __ballot(noi[tg] != 0.f);
    if ((threadIdx.x & 63u) == 0u) nb[tg >> 6] = m;
    return;
  }
  unsigned tg = blk * 256u + threadIdx.x;  // element index into [64][256][256]
  u64 m = __ballot(mat[tg] != 0.f);
  if ((threadIdx.x & 63u) == 0u) wb[tg >> 6] = m;
}

// ---- chain-of-4 compose on one block's LDS state (proven R8/R9 algorithm,
// R10: B rows/vector-words preloaded to registers -> no global in the loop).
// (A,a) <- compose maps [base, base+4): A <- B*A, a <- B*a ^ b per step. ----
__device__ __forceinline__ void fold_chain(u64 (&A)[256][5], u64 (&tbl)[64][16][5],
                                           u64 (&avec)[4],
                                           const u64* __restrict__ inM,
                                           const u64* __restrict__ inV,
                                           int base, int tid, int w, int i) {
  A[i][w] = inM[(size_t)base * 1024 + i * 4 + w];
  if (tid < 4) avec[tid] = inV[base * 4 + tid];
  u64 br[3][4], bw[3];
#pragma unroll
  for (int j = 0; j < 3; ++j) {
    const u64* Bm = inM + (size_t)(base + 1 + j) * 1024;
#pragma unroll
    for (int q = 0; q < 4; ++q) br[j][q] = Bm[i * 4 + q];
    bw[j] = (tid < 256) ? inV[(size_t)(base + 1 + j) * 4 + (i >> 6)] : 0ull;
  }
  __syncthreads();

#pragma unroll
  for (int j = 0; j < 3; ++j) {
    u64 av0 = avec[0], av1 = avec[1], av2 = avec[2], av3 = avec[3];
    // build 4-bit combination table over A's rows (contraction index k)
    {
      const int c = tid >> 4, m = tid & 15;  // 1024 entries, 1/thread
      u64 t0 = 0, t1 = 0, t2 = 0, t3 = 0;
#pragma unroll
      for (int jj = 0; jj < 4; ++jj)
        if (m & (1 << jj)) {
          t0 ^= A[4 * c + jj][0]; t1 ^= A[4 * c + jj][1];
          t2 ^= A[4 * c + jj][2]; t3 ^= A[4 * c + jj][3];
        }
      tbl[c][m][0] = t0; tbl[c][m][1] = t1; tbl[c][m][2] = t2; tbl[c][m][3] = t3;
    }
    __syncthreads();

    // R[i] = XOR_{k: B[i][k]=1} A[k], word w — 4-way ILP over the 64 gathers
    u64 a0 = 0, a1 = 0, a2 = 0, a3 = 0;
#pragma unroll
    for (int c = 0; c < 64; c += 4) {
      unsigned n0 = (unsigned)(br[j][(c + 0) >> 4] >> (((c + 0) & 15) * 4)) & 15u;
      unsigned n1 = (unsigned)(br[j][(c + 1) >> 4] >> (((c + 1) & 15) * 4)) & 15u;
      unsigned n2 = (unsigned)(br[j][(c + 2) >> 4] >> (((c + 2) & 15) * 4)) & 15u;
      unsigned n3 = (unsigned)(br[j][(c + 3) >> 4] >> (((c + 3) & 15) * 4)) & 15u;
      a0 ^= tbl[c + 0][n0][w];
      a1 ^= tbl[c + 1][n1][w];
      a2 ^= tbl[c + 2][n2][w];
      a3 ^= tbl[c + 3][n3][w];
    }
    u64 acc = (a0 ^ a1) ^ (a2 ^ a3);

    // a' = B*a ^ b : bit i = parity(popcount(Brow_i & a)) ^ b_i (waves 0..3)
    u64 mask = 0;
    if (tid < 256) {
      int p = __popcll(br[j][0] & av0) + __popcll(br[j][1] & av1) +
              __popcll(br[j][2] & av2) + __popcll(br[j][3] & av3);
      int bit = ((int)((bw[j] >> (i & 63)) & 1ull)) ^ (p & 1);
      mask = __ballot(bit);
    }
    __syncthreads();  // tbl/avec reads done before overwrite
    A[i][w] = acc;
    if (tid < 256 && (i & 63) == 0) avec[i >> 6] = mask;
    __syncthreads();
  }
}

// ---- 2) foldall (cooperative): 3 tree levels + inline packm, one dispatch.
__global__ __launch_bounds__(1024) void foldall(const u64* __restrict__ Wb,
                                                const u64* __restrict__ nb,
                                                u64* __restrict__ G1M,
                                                u64* __restrict__ G1V,
                                                u64* __restrict__ G2M,
                                                u64* __restrict__ G2V,
                                                uint32_t* __restrict__ wpk,
                                                float* __restrict__ nf) {
  __shared__ u64 A[256][5];       // padded (bank spread)
  __shared__ u64 tbl[64][16][5];
  __shared__ u64 avec[4];
  const int tid = threadIdx.x;
  const int w = tid >> 8;   // 0..3
  const int i = tid & 255;  // 0..255
  cg::grid_group grid = cg::this_grid();

  // level 1: 16 blocks, chains of 4 rounds
  fold_chain(A, tbl, avec, Wb, nb, blockIdx.x * 4, tid, w, i);
  G1M[(size_t)blockIdx.x * 1024 + i * 4 + w] = A[i][w];
  if (tid < 4) G1V[blockIdx.x * 4 + tid] = avec[tid];
  __threadfence();
  grid.sync();

  // level 2: blocks 0..3, chains of 4 partials
  if (blockIdx.x < 4) {
    fold_chain(A, tbl, avec, G1M, G1V, blockIdx.x * 4, tid, w, i);
    G2M[(size_t)blockIdx.x * 1024 + i * 4 + w] = A[i][w];
    if (tid < 4) G2V[blockIdx.x * 4 + tid] = avec[tid];
  }
  __threadfence();
  grid.sync();

  // level 3 + packm: block 0 only; final M lives in LDS A, c in avec
  if (blockIdx.x == 0) {
    fold_chain(A, tbl, avec, G2M, G2V, 0, tid, w, i);
    // pack M bits -> fp4 A-fragments (proven pack_w4 layout, M in {0,1})
#pragma unroll
    for (int it = 0; it < 2; ++it) {
      unsigned tg = (unsigned)it * 1024u + tid;  // row*8 + kwin, 2048 total
      unsigned kwin = tg & 7u, row = tg >> 3;
      uint32_t wd[4] = {0, 0, 0, 0};
#pragma unroll
      for (int n = 0; n < 32; ++n) {
        int k = (int)kwin * 32 + rho(n);
        uint32_t bit = (uint32_t)((A[row][k >> 6] >> (k & 63)) & 1ull);
        wd[n >> 3] |= (bit * 2u) << ((n & 7) * 4);  // fp4 e2m1: +1 -> 0b0010
      }
      unsigned mt = row >> 5, lhh = kwin & 1u, ks = kwin >> 1;
      unsigned lane = lhh * 32u + (row & 31u);
      *(uint4*)(wpk + (((mt * 4u + ks) * 64u + lane) << 2)) =
          make_uint4(wd[0], wd[1], wd[2], wd[3]);
    }
    if (tid < 256) {  // nf[mt][lh][j] = c[row(j,lh,mt)]
      unsigned j = tid & 15u, lhh = (tid >> 4) & 1u, mt = (unsigned)tid >> 5;
      unsigned row = mt * 32u + (j & 3u) + 8u * (j >> 2) + 4u * lhh;
      nf[tid] = (float)((avec[row >> 6] >> (row & 63u)) & 1ull);
    }
  }
}

// ---- 3) hash1: the PROVEN R3 hash4 structure with exactly ONE round.
// out = (M s0 + c) mod 2 via fp4 MFMA 32x32x64, K=256 in 4 steps, c as MFMA
// C-init, bias-trick epilogue. 512 thr, 128 el/block, wave wv = M-tile wv. ----
__global__ __launch_bounds__(512, 4) void hash1(const uint32_t* __restrict__ wpk,
                                                const float* __restrict__ nf,
                                                const float* __restrict__ sta,
                                                float* __restrict__ out) {
  __shared__ uint8_t T[2][8][128][16];  // 32 KB
  const int t = threadIdx.x;
  const int wv = __builtin_amdgcn_readfirstlane(t >> 6);
  const int lane = t & 63;
  const int l31 = lane & 31;
  const int lh = lane >> 5;
  const int el0 = blockIdx.x * 128;

  // initial pack: f32 -> sigma-ordered fp4 nibbles into T[0]
#pragma unroll
  for (int i = 0; i < 16; ++i) {
    unsigned flat = (unsigned)i * 512u + t;
    unsigned el = flat >> 6, k4 = flat & 63u;
    float4 f = ((const float4*)(sta + (size_t)el0 * 256))[flat];
    uint32_t v = ((f.x != 0.f) ? 0x2u : 0u) | ((f.y != 0.f) ? 0x20u : 0u) |
                 ((f.z != 0.f) ? 0x200u : 0u) | ((f.w != 0.f) ? 0x2000u : 0u);
    unsigned KB = k4 >> 3, k4c = k4 & 7u;
    unsigned byteoff = (k4c & 1u) * 8u + 2u * (k4c >> 1);
    *(uint16_t*)&T[0][KB][el][byteoff] = (uint16_t)v;
  }
  __syncthreads();

  v4i ap[4];
  {
    const uint32_t* wb = wpk + ((wv * 4) << 8);
#pragma unroll
    for (int ks = 0; ks < 4; ++ks) ap[ks] = *(const v4i*)(wb + ks * 256 + lane * 4);
  }
  v16f NZ = *(const v16f*)(nf + (wv * 2 + lh) * 16);

  v16f acc[4];
  __builtin_amdgcn_s_setprio(1);
#pragma unroll
  for (int ks = 0; ks < 4; ++ks) {
    v8i A8 = __builtin_shufflevector(ap[ks], ap[ks], 0, 1, 2, 3, -1, -1, -1, -1);
    const int kb = 2 * ks + lh;
#pragma unroll
    for (int tn = 0; tn < 4; ++tn) {
      v4i b4 = *(const v4i*)&T[0][kb][tn * 32 + l31][0];
      v8i B8 = __builtin_shufflevector(b4, b4, 0, 1, 2, 3, -1, -1, -1, -1);
      acc[tn] = __builtin_amdgcn_mfma_scale_f32_32x32x64_f8f6f4(
          A8, B8, (ks == 0) ? NZ : acc[tn], 4, 4, 0, 127, 0, 127);
    }
  }
  __builtin_amdgcn_s_setprio(0);

  // epilogue -> T[1]
#pragma unroll
  for (int tn = 0; tn < 4; ++tn) {
#define PB(j)                                                          \
  (__builtin_bit_cast(uint32_t, acc[tn][j] + bias_q((j) & 3)) &        \
   (2u << (4 * ((j) & 3))))
    uint32_t u0 = PB(0) | PB(1) | PB(2) | PB(3);
    uint32_t u1 = PB(4) | PB(5) | PB(6) | PB(7);
    uint32_t u2 = PB(8) | PB(9) | PB(10) | PB(11);
    uint32_t u3 = PB(12) | PB(13) | PB(14) | PB(15);
#undef PB
    *(uint2*)&T[1][wv][tn * 32 + l31][lh * 8] =
        make_uint2(u0 | (u1 << 16), u2 | (u3 << 16));
  }
  __syncthreads();

  // unpack T[1] -> out
#pragma unroll
  for (int i = 0; i < 16; ++i) {
    unsigned flat = (unsigned)i * 512u + t;
    unsigned el = flat >> 6, k4 = flat & 63u;
    unsigned KB = k4 >> 3, k4c = k4 & 7u;
    unsigned byteoff = (k4c & 1u) * 8u + 2u * (k4c >> 1);
    uint32_t v = *(const uint16_t*)&T[1][KB][el][byteoff];
    float4 o = make_float4((float)((v >> 1) & 1u), (float)((v >> 5) & 1u),
                           (float)((v >> 9) & 1u), (float)((v >> 13) & 1u));
    ((float4*)(out + (size_t)el0 * 256))[flat] = o;
  }
}

extern "C" void kernel_launch(void* const* d_in, const int* in_sizes, int n_in,
                              void* d_out, int out_size, void* d_ws, size_t ws_size,
                              hipStream_t stream) {
  const float* sta = (const float*)d_in[0];  // [B, HIDDEN]
  const float* mat = (const float*)d_in[1];  // [ROUNDS, HIDDEN, HIDDEN]
  const float* noi = (const float*)d_in[2];  // [ROUNDS, HIDDEN]
  uint8_t* wsb = (uint8_t*)d_ws;             // needs ~725 KB

  u64* Wb       = (u64*)(wsb + WB_OFF);
  u64* nb       = (u64*)(wsb + NB_OFF);
  u64* G1M      = (u64*)(wsb + G1M_OFF);
  u64* G1V      = (u64*)(wsb + G1V_OFF);
  u64* G2M      = (u64*)(wsb + G2M_OFF);
  u64* G2V      = (u64*)(wsb + G2V_OFF);
  uint32_t* wpk = (uint32_t*)(wsb + WPK_OFF);
  float* nf     = (float*)(wsb + NF_OFF);

  bitpack<<<16448, 256, 0, stream>>>(mat, noi, Wb, nb);

  void* kargs[8] = {&Wb, &nb, &G1M, &G1V, &G2M, &G2V, &wpk, &nf};
  hipLaunchCooperativeKernel((const void*)foldall, dim3(16), dim3(1024), kargs,
                             0, stream);

  hash1<<<512, 512, 0, stream>>>(wpk, nf, sta, (float*)d_out);
}